// Round 1
// baseline (779.596 us; speedup 1.0000x reference)
//
#include <hip/hip_runtime.h>

// Dynamic filter layer, 'valid', stride 1:
// out[b,i,j,c] = sum_{di,dj} x[b,i+di,j+dj,c] * flow[b,i,j,di*K+dj]
// B=8, H=W=256, C=64, K=5, Ho=Wo=252. All fp32.
//
// R3: latency-bound fix.
//  - x tile staged into LDS via async global_load_lds (width 16), rolling
//    2-row double-buffered window: stage group g+1 issued BEFORE compute of
//    group g, __syncthreads' vmcnt(0) drain is the pipeline wait.
//  - flow weights in LDS padded to 8 floats per filter row -> one
//    ds_read_b128 + one ds_read_b32 per (ii,di) instead of 5 scalar reads
//    (150 -> 60 LDS instrs/thread). Bank stride 40 words: jj lanes on
//    banks {0,8,16,24}, conflict-free; q lanes broadcast.
//  - LDS 35.8 KB -> 4 blocks/CU; __launch_bounds__(256,4) caps VGPR at 128.

constexpr int B  = 8;
constexpr int H  = 256;
constexpr int W  = 256;
constexpr int C  = 64;
constexpr int K  = 5;
constexpr int Ho = H - K + 1;            // 252
constexpr int Wo = W - K + 1;            // 252
constexpr int CQ = C / 4;                // 16 float4 quads per pixel
constexpr int R  = 6;                    // output rows per block (Ho % R == 0)
constexpr int SEG = Ho / R;              // 42 row segments
constexpr int JT  = 16;                  // j-pixels per block
constexpr int JB  = (Wo + JT - 1) / JT;  // 16 j blocks (last partial)
constexpr int PX  = JT + K - 1;          // 20 x-pixels staged per row
constexpr int ROWF = PX * C;             // 1280 floats (5 KiB) per staged row
constexpr int NR  = R + K - 1;           // 10 x rows needed
constexpr int GRP = 2;                   // rows per stage group
constexpr int NG  = NR / GRP;            // 5 groups
constexpr int FROW = 8;                  // filter row padded 5 -> 8 floats
constexpr int CPR  = ROWF / 4;           // 320 16B-chunks per row
constexpr int SPR  = CPR / 64;           // 5 wave-slabs per row
constexpr int SLABS = GRP * SPR;         // 10 wave-slabs per group

__device__ __forceinline__ void async_copy16(const float* g, float* l) {
    // global -> LDS, 16 B per lane. LDS dest = wave-uniform base + lane*16.
    __builtin_amdgcn_global_load_lds(
        (const __attribute__((address_space(1))) void*)g,
        (__attribute__((address_space(3))) void*)l, 16, 0, 0);
}

__global__ __launch_bounds__(256, 4) void dfl_kernel(
    const float* __restrict__ x,
    const float* __restrict__ flow,
    float* __restrict__ out)
{
    __shared__ float sx[2 * GRP * ROWF];        // 20 KiB (double-buffered x)
    __shared__ float sf[R * JT * K * FROW];     // 15 KiB (padded flow)

    const int t  = threadIdx.x;
    const int q  = t & (CQ - 1);          // channel quad 0..15
    const int jj = t >> 4;                // j within block 0..15
    const int wv = t >> 6;                // wave 0..3
    const int ln = t & 63;                // lane 0..63

    int bid = blockIdx.x;
    const int jb  = bid % JB;  bid /= JB;
    const int seg = bid % SEG; bid /= SEG;
    const int b   = bid;

    const int j0 = jb * JT;
    const int j  = j0 + jj;
    const int i0 = seg * R;

    const float* xbase = x + ((size_t)(b * H + i0) * W + j0) * C;
    const float* xmax  = x + (size_t)B * H * W * C - 4;   // last full float4

    // ---- flow staging: [ii][jj][di][FROW], coalesced reads, padded writes ----
    {
        const float* fsrc = flow + ((size_t)(b * Ho + i0) * Wo + j0) * (K * K);
        #pragma unroll
        for (int step = 0; step < (R * JT * K * K + 255) / 256; ++step) {
            const int e = step * 256 + t;
            if (e < R * JT * K * K) {
                const int ii  = e / (JT * K * K);
                const int rem = e - ii * (JT * K * K);
                const int pj  = rem / (K * K);
                const int tap = rem - pj * (K * K);
                const int di  = tap / K;
                const int dj  = tap - di * K;
                float v = 0.f;
                if (j0 + pj < Wo)                   // guard: last j-block OOB
                    v = fsrc[(size_t)ii * (Wo * K * K) + pj * (K * K) + tap];
                sf[((ii * JT + pj) * K + di) * FROW + dj] = v;
            }
        }
    }

    // ---- async stage of x row-group g into sx[g&1] ----
    auto stage_group = [&](int g) {
        const int buf = g & 1;
        #pragma unroll
        for (int s3 = 0; s3 < 3; ++s3) {
            const int s = wv + s3 * 4;            // wave-slab id 0..9
            if (s < SLABS) {
                const int rr  = s / SPR;          // row within group (0..1)
                const int cc0 = (s - rr * SPR) * 64;     // chunk base in row
                const int row = g * GRP + rr;            // 0..9
                const float* src = xbase + (size_t)row * (W * C)
                                         + (size_t)(cc0 + ln) * 4;
                if (src > xmax) src = xmax;       // clamp: very last row halo
                async_copy16(src, &sx[(buf * GRP + rr) * ROWF + cc0 * 4]);
            }
        }
    };

    float4 acc[R];
    #pragma unroll
    for (int ii = 0; ii < R; ++ii) acc[ii] = make_float4(0.f, 0.f, 0.f, 0.f);

    stage_group(0);
    __syncthreads();                       // drains vmcnt(0): group 0 ready

    #pragma unroll
    for (int g = 0; g < NG; ++g) {
        if (g + 1 < NG) stage_group(g + 1);   // issue BEFORE compute: overlap
        const int buf = g & 1;
        #pragma unroll
        for (int rr = 0; rr < GRP; ++rr) {
            const int r = g * GRP + rr;            // compile-time (full unroll)
            const float* xr = &sx[(buf * GRP + rr) * ROWF];
            float4 xv[K];
            #pragma unroll
            for (int dj = 0; dj < K; ++dj)
                xv[dj] = *(const float4*)&xr[(jj + dj) * C + (q << 2)];
            #pragma unroll
            for (int ii = 0; ii < R; ++ii) {
                const int di = r - ii;             // tap row for output ii
                if (di < 0 || di >= K) continue;   // compile-time resolved
                const float4 w4 = *(const float4*)&sf[((ii * JT + jj) * K + di) * FROW];
                const float  w5 = sf[((ii * JT + jj) * K + di) * FROW + 4];
                const float wt[K] = {w4.x, w4.y, w4.z, w4.w, w5};
                #pragma unroll
                for (int dj = 0; dj < K; ++dj) {
                    acc[ii].x += xv[dj].x * wt[dj];
                    acc[ii].y += xv[dj].y * wt[dj];
                    acc[ii].z += xv[dj].z * wt[dj];
                    acc[ii].w += xv[dj].w * wt[dj];
                }
            }
        }
        __syncthreads();   // vmcnt(0)+barrier: group g+1 staged, buf g reusable
    }

    if (j < Wo) {
        float4* ob = (float4*)out + ((size_t)(b * Ho + i0) * Wo + j) * CQ + q;
        #pragma unroll
        for (int ii = 0; ii < R; ++ii)
            ob[(size_t)ii * (Wo * CQ)] = acc[ii];
    }
}

extern "C" void kernel_launch(void* const* d_in, const int* in_sizes, int n_in,
                              void* d_out, int out_size, void* d_ws, size_t ws_size,
                              hipStream_t stream) {
    const float* x    = (const float*)d_in[0];
    const float* flow = (const float*)d_in[1];
    // d_in[2] is ksize (scalar), fixed at 5 — baked in as constexpr.
    float* out = (float*)d_out;

    const int grid = B * SEG * JB;        // 8 * 42 * 16 = 5376 blocks
    dfl_kernel<<<grid, 256, 0, stream>>>(x, flow, out);
}

// Round 2
// 297.942 us; speedup vs baseline: 2.6166x; 2.6166x over previous
//
#include <hip/hip_runtime.h>

// Dynamic filter layer, 'valid', stride 1:
// out[b,i,j,c] = sum_{di,dj} x[b,i+di,j+dj,c] * flow[b,i,j,di*K+dj]
// B=8, H=W=256, C=64, K=5, Ho=Wo=252. All fp32.
//
// R4: R2 structure (direct per-thread float4 x loads -> cache-absorbed),
// with three targeted fixes for the latency-bound profile:
//  1. flow weights in LDS padded to 8 floats per filter row:
//     ds_read_b128 + ds_read_b32 per (ii,di) -> 60 LDS ops/thread (was 150
//     scalar b32). Bank stride 40 words: jj lanes on banks {0,8,16,24},
//     conflict-free; q lanes broadcast.
//  2. explicit 2-row-ahead x prefetch via 3-buffer register ring
//     (compile-time %3 indices only -- no scratch). Load->use distance
//     ~2 FMA blocks covers L1/L2 hit latency.
//  3. nontemporal output stores: out (121 MB) never re-read; keeps
//     x (134 MB) + flow (51 MB) resident in the 256 MB L3 across iters.
// NO global_load_lds for x: R3 proved LDS-DMA wrecks the cache-absorption
// this stencil depends on (FETCH 107->803 MB, WRITE 127->1454 MB).

constexpr int B  = 8;
constexpr int H  = 256;
constexpr int W  = 256;
constexpr int C  = 64;
constexpr int K  = 5;
constexpr int Ho = H - K + 1;            // 252
constexpr int Wo = W - K + 1;            // 252
constexpr int CQ = C / 4;                // 16 float4 quads per pixel
constexpr int R  = 6;                    // outputs per thread along i (Ho % R == 0)
constexpr int SEG = Ho / R;              // 42 row segments
constexpr int JT  = 16;                  // j-pixels per block (16 j x 16 q = 256 thr)
constexpr int JB  = (Wo + JT - 1) / JT;  // 16 j blocks (last partial)
constexpr int NR  = R + K - 1;           // 10 x rows touched per block
constexpr int FROW = 8;                  // filter row padded 5 -> 8 floats

typedef float vf4 __attribute__((ext_vector_type(4)));

__global__ __launch_bounds__(256) void dfl_kernel(
    const float* __restrict__ x,
    const float* __restrict__ flow,
    float* __restrict__ out)
{
    __shared__ float sf[R * JT * K * FROW];   // 15 KiB, padded flow

    const int t  = threadIdx.x;
    const int q  = t & (CQ - 1);          // channel quad 0..15
    const int jj = t >> 4;                // j within block 0..15

    int bid = blockIdx.x;
    const int jb  = bid % JB;  bid /= JB;
    const int seg = bid % SEG; bid /= SEG;
    const int b   = bid;

    const int j0 = jb * JT;
    const int j  = j0 + jj;
    const int i0 = seg * R;

    // ---- Stage flow tile: [ii][jj][di][FROW], coalesced reads ----
    {
        const float* fsrc = flow + ((size_t)(b * Ho + i0) * Wo + j0) * (K * K);
        #pragma unroll
        for (int step = 0; step < (R * JT * K * K + 255) / 256; ++step) {
            const int e = step * 256 + t;
            if (e < R * JT * K * K) {
                const int ii  = e / (JT * K * K);
                const int rem = e - ii * (JT * K * K);
                const int pj  = rem / (K * K);
                const int tap = rem - pj * (K * K);
                const int di  = tap / K;
                const int dj  = tap - di * K;
                float v = 0.f;
                if (j0 + pj < Wo)                 // guard: last j-block OOB
                    v = fsrc[(size_t)ii * (Wo * K * K) + pj * (K * K) + tap];
                sf[((ii * JT + pj) * K + di) * FROW + dj] = v;
            }
        }
    }
    __syncthreads();

    // ---- Compute: vertical sliding window, 2-row-ahead prefetch ring ----
    const int jx = j < Wo ? j : Wo - 1;   // clamp for edge block (store guarded)
    const float4* xq = (const float4*)x + ((size_t)(b * H + i0) * W + jx) * CQ + q;

    float4 acc[R];
    #pragma unroll
    for (int ii = 0; ii < R; ++ii) acc[ii] = make_float4(0.f, 0.f, 0.f, 0.f);

    float4 xb[3][K];                      // 3-row register ring (60 VGPRs)
    #pragma unroll
    for (int dj = 0; dj < K; ++dj) xb[0][dj] = xq[dj * CQ];
    #pragma unroll
    for (int dj = 0; dj < K; ++dj) xb[1][dj] = xq[(size_t)(W * CQ) + dj * CQ];

    #pragma unroll
    for (int r = 0; r < NR; ++r) {        // fully unrolled: all indices static
        if (r + 2 < NR) {                 // issue row r+2 before computing row r
            #pragma unroll
            for (int dj = 0; dj < K; ++dj)
                xb[(r + 2) % 3][dj] = xq[(size_t)(r + 2) * (W * CQ) + dj * CQ];
        }
        const float4* xrow = xb[r % 3];
        #pragma unroll
        for (int ii = 0; ii < R; ++ii) {
            const int di = r - ii;             // tap row for output ii
            if (di < 0 || di >= K) continue;   // compile-time resolved
            const float* fp = &sf[((ii * JT + jj) * K + di) * FROW];
            const vf4   w4 = *(const vf4*)fp;  // ds_read_b128
            const float w5 = fp[4];            // ds_read_b32
            const float wt[K] = {w4.x, w4.y, w4.z, w4.w, w5};
            #pragma unroll
            for (int dj = 0; dj < K; ++dj) {
                acc[ii].x += xrow[dj].x * wt[dj];
                acc[ii].y += xrow[dj].y * wt[dj];
                acc[ii].z += xrow[dj].z * wt[dj];
                acc[ii].w += xrow[dj].w * wt[dj];
            }
        }
    }

    if (j < Wo) {
        float* ob = out + (((size_t)(b * Ho + i0) * Wo + j) * CQ + q) * 4;
        #pragma unroll
        for (int ii = 0; ii < R; ++ii) {
            vf4 v = {acc[ii].x, acc[ii].y, acc[ii].z, acc[ii].w};
            __builtin_nontemporal_store(v, (vf4*)(ob + (size_t)ii * (Wo * CQ) * 4));
        }
    }
}

extern "C" void kernel_launch(void* const* d_in, const int* in_sizes, int n_in,
                              void* d_out, int out_size, void* d_ws, size_t ws_size,
                              hipStream_t stream) {
    const float* x    = (const float*)d_in[0];
    const float* flow = (const float*)d_in[1];
    // d_in[2] is ksize (scalar), fixed at 5 — baked in as constexpr.
    float* out = (float*)d_out;

    const int grid = B * SEG * JB;        // 8 * 42 * 16 = 5376 blocks
    dfl_kernel<<<grid, 256, 0, stream>>>(x, flow, out);
}